// Round 5
// baseline (748.704 us; speedup 1.0000x reference)
//
#include <hip/hip_runtime.h>
#include <hip/hip_cooperative_groups.h>

namespace cg = cooperative_groups;

#define SPATIAL 32768   // 32^3
#define NBINS   131072  // B(=4) * 32^3
#define FDIM    64
#define BLOCKS  1024
#define TPB     256
#define NTHREADS (BLOCKS * TPB)

// ws word layout:
//   [0, NBINS)       counts -> offsets -> cursor (transformed in place)
//   [NBINS]          tail
//   [NBINS+1..+2]    mm: enc-min, ~enc-max (memset 0xFF; both atomicMin)
//   [NBINS+3]        pad
//   [NBINS+4, ...)   ord2: uint2 (point, bin) per slot, bin-grouped. 8B-aligned.

__device__ __forceinline__ unsigned enc_f32(float f) {
    unsigned u = __float_as_uint(f);
    return (u & 0x80000000u) ? ~u : (u | 0x80000000u);
}
__device__ __forceinline__ float dec_f32(unsigned u) {
    u = (u & 0x80000000u) ? (u ^ 0x80000000u) : ~u;
    return __uint_as_float(u);
}

__device__ __forceinline__ unsigned compute_bin(const float* __restrict__ pts,
                                                int p, int N,
                                                float pmin, float denom) {
    float x = pts[p * 3 + 0];
    float y = pts[p * 3 + 1];
    float z = pts[p * 3 + 2];
    // exact op order of reference: normed = (v-pmin)/denom; floor(normed*32)
    int vx = (int)floorf(((x - pmin) / denom) * 32.0f);
    int vy = (int)floorf(((y - pmin) / denom) * 32.0f);
    int vz = (int)floorf(((z - pmin) / denom) * 32.0f);
    vx = min(max(vx, 0), 31);
    vy = min(max(vy, 0), 31);
    vz = min(max(vz, 0), 31);
    int b = p / N;
    return (unsigned)b * SPATIAL + (unsigned)(vx * 1024 + vy * 32 + vz);
}

// ---------- phase device functions (shared by fused + fallback paths) ----------

__device__ void ph_minmax(const float* __restrict__ pts, int n,
                          unsigned* __restrict__ mm, int tid, int nthreads) {
    float lmin = INFINITY, lmax = -INFINITY;
    int n4 = n >> 2;
    const float4* p4 = (const float4*)pts;
    for (int i = tid; i < n4; i += nthreads) {
        float4 v = p4[i];
        lmin = fminf(fminf(lmin, v.x), fminf(v.y, v.z)); lmin = fminf(lmin, v.w);
        lmax = fmaxf(fmaxf(lmax, v.x), fmaxf(v.y, v.z)); lmax = fmaxf(lmax, v.w);
    }
    for (int i = (n4 << 2) + tid; i < n; i += nthreads) {
        float v = pts[i];
        lmin = fminf(lmin, v); lmax = fmaxf(lmax, v);
    }
#pragma unroll
    for (int d = 1; d < 64; d <<= 1) {
        lmin = fminf(lmin, __shfl_xor(lmin, d, 64));
        lmax = fmaxf(lmax, __shfl_xor(lmax, d, 64));
    }
    if ((threadIdx.x & 63) == 0) {
        atomicMin(&mm[0], enc_f32(lmin));
        atomicMin(&mm[1], ~enc_f32(lmax));
    }
}

__device__ void ph_bincount(const float* __restrict__ pts,
                            const unsigned* __restrict__ mm,
                            unsigned* __restrict__ counts,
                            int ntot, int N, int tid, int nthreads) {
    float pmin = dec_f32(mm[0]);
    float denom = dec_f32(~mm[1]) - pmin + 1e-6f;
    for (int p = tid; p < ntot; p += nthreads) {
        unsigned bin = compute_bin(pts, p, N, pmin, denom);
        atomicAdd(&counts[bin], 1u);
    }
}

// In-place counts -> exclusive segment offsets, wave-aggregated tail alloc.
// NBINS and nthreads are multiples of 64 so the i<NBINS test is wave-uniform.
__device__ void ph_offsets(unsigned* __restrict__ counts,
                           unsigned* __restrict__ tail, int tid, int nthreads) {
    int lane = threadIdx.x & 63;
    for (int i = tid; i < NBINS; i += nthreads) {
        unsigned cnt = counts[i];
        unsigned cs = cnt;
#pragma unroll
        for (int d = 1; d < 64; d <<= 1) {
            unsigned v = __shfl_up(cs, (unsigned)d, 64);
            if (lane >= d) cs += v;
        }
        unsigned ctot = __shfl(cs, 63, 64);
        unsigned base = 0;
        if (lane == 63 && ctot) base = atomicAdd(tail, ctot);
        base = __shfl(base, 63, 64);
        if (cnt) counts[i] = base + cs - cnt;   // exclusive offset
    }
}

__device__ void ph_build(const float* __restrict__ pts,
                         const unsigned* __restrict__ mm,
                         unsigned* __restrict__ cursor,
                         uint2* __restrict__ ord2,
                         int ntot, int N, int tid, int nthreads) {
    float pmin = dec_f32(mm[0]);
    float denom = dec_f32(~mm[1]) - pmin + 1e-6f;
    for (int p = tid; p < ntot; p += nthreads) {
        unsigned bin = compute_bin(pts, p, N, pmin, denom);
        unsigned pos = atomicAdd(&cursor[bin], 1u);
        ord2[pos] = make_uint2((unsigned)p, bin);
    }
}

// Balanced gather: each wave takes fixed 64-slot chunks of the bin-grouped
// (point,bin) array. Runs of equal bin fold in-register; each run flushes with
// one wave-wide atomicMax (negative maxima skipped: grid zero-init wins).
__device__ void ph_gather(const float* __restrict__ feat,
                          const uint2* __restrict__ ord2,
                          int ntot, unsigned* __restrict__ out,
                          int tid, int nthreads) {
    int lane = threadIdx.x & 63;
    unsigned wave = (unsigned)tid >> 6;
    unsigned nwaves = (unsigned)nthreads >> 6;
    unsigned nchunks = ((unsigned)ntot + 63u) >> 6;

    for (unsigned c = wave; c < nchunks; c += nwaves) {
        unsigned base = c << 6;
        unsigned nb = min(64u, (unsigned)ntot - base);
        uint2 e = (lane < (int)nb) ? ord2[base + lane]
                                   : make_uint2(0u, 0xFFFFFFFFu);
        unsigned pv = e.x;
        unsigned bv = e.y;

        float m = 0.0f;
        for (unsigned j0 = 0; j0 < nb; j0 += 16) {
            unsigned kn = min(16u, nb - j0);
            float f[16];
#pragma unroll
            for (unsigned k = 0; k < 16; ++k) {
                if (k < kn) {
                    unsigned p = __shfl(pv, (int)(j0 + k), 64);
                    f[k] = feat[(size_t)p * FDIM + lane];
                }
            }
#pragma unroll
            for (unsigned k = 0; k < 16; ++k) {
                if (k < kn) {
                    unsigned idx = j0 + k;
                    unsigned b  = __shfl(bv, (int)idx, 64);
                    unsigned bn = (idx + 1 < nb) ? __shfl(bv, (int)(idx + 1), 64)
                                                 : 0xFFFFFFFFu;
                    m = fmaxf(m, f[k]);
                    if (b != bn) {  // wave-uniform branch
                        if (m > 0.0f)
                            atomicMax(&out[(size_t)b * FDIM + lane],
                                      __float_as_uint(m));
                        m = 0.0f;
                    }
                }
            }
        }
    }
}

// ---------- fused cooperative kernel ----------
__global__ void __launch_bounds__(TPB, 4)
fused_kernel(const float* __restrict__ pts, const float* __restrict__ feat,
             unsigned* __restrict__ ws, unsigned* __restrict__ out,
             int ntot, int npts3, int N) {
    cg::grid_group grid = cg::this_grid();
    int tid = blockIdx.x * blockDim.x + threadIdx.x;
    unsigned* counts = ws;
    unsigned* tail   = ws + NBINS;
    unsigned* mm     = ws + NBINS + 1;
    uint2*    ord2   = (uint2*)(ws + NBINS + 4);

    ph_minmax(pts, npts3, mm, tid, NTHREADS);
    grid.sync();
    ph_bincount(pts, mm, counts, ntot, N, tid, NTHREADS);
    grid.sync();
    ph_offsets(counts, tail, tid, NTHREADS);
    grid.sync();
    ph_build(pts, mm, counts, ord2, ntot, N, tid, NTHREADS);
    grid.sync();
    ph_gather(feat, ord2, ntot, out, tid, NTHREADS);
}

// ---------- fallback: same phases as separate dispatches ----------
__global__ void k_minmax(const float* pts, int n, unsigned* mm) {
    ph_minmax(pts, n, mm, blockIdx.x * blockDim.x + threadIdx.x,
              gridDim.x * blockDim.x);
}
__global__ void k_bincount(const float* pts, const unsigned* mm,
                           unsigned* counts, int ntot, int N) {
    ph_bincount(pts, mm, counts, ntot, N,
                blockIdx.x * blockDim.x + threadIdx.x, gridDim.x * blockDim.x);
}
__global__ void k_offsets(unsigned* counts, unsigned* tail) {
    ph_offsets(counts, tail, blockIdx.x * blockDim.x + threadIdx.x,
               gridDim.x * blockDim.x);
}
__global__ void k_build(const float* pts, const unsigned* mm, unsigned* cursor,
                        uint2* ord2, int ntot, int N) {
    ph_build(pts, mm, cursor, ord2, ntot, N,
             blockIdx.x * blockDim.x + threadIdx.x, gridDim.x * blockDim.x);
}
__global__ void k_gather(const float* feat, const uint2* ord2, int ntot,
                         unsigned* out) {
    ph_gather(feat, ord2, ntot, out,
              blockIdx.x * blockDim.x + threadIdx.x, gridDim.x * blockDim.x);
}

// ---------- last-resort fallback (round-1 atomic scatter) ----------
__global__ void scatter_kernel(const float* __restrict__ pts,
                               const float* __restrict__ feat,
                               const unsigned* __restrict__ mm,
                               unsigned* __restrict__ out, int ntot, int N) {
    int lane = threadIdx.x & 63;
    int p = blockIdx.x * 4 + (threadIdx.x >> 6);
    if (p >= ntot) return;
    float pmin = dec_f32(mm[0]);
    float denom = dec_f32(~mm[1]) - pmin + 1e-6f;
    unsigned bin = compute_bin(pts, p, N, pmin, denom);
    float f = feat[(size_t)p * FDIM + lane];
    if (f > 0.0f)
        atomicMax(&out[(size_t)bin * FDIM + lane], __float_as_uint(f));
}

extern "C" void kernel_launch(void* const* d_in, const int* in_sizes, int n_in,
                              void* d_out, int out_size, void* d_ws, size_t ws_size,
                              hipStream_t stream) {
    const float* pts = (const float*)d_in[0];
    const float* feat = (const float*)d_in[1];

    int npts3 = in_sizes[0];   // B*N*3
    int ntot = npts3 / 3;      // B*N
    int B = out_size / (SPATIAL * FDIM);
    int N = ntot / B;

    unsigned* ws = (unsigned*)d_ws;
    unsigned* counts = ws;
    unsigned* tail   = ws + NBINS;
    unsigned* mm     = ws + NBINS + 1;
    uint2*    ord2   = (uint2*)(ws + NBINS + 4);
    unsigned* outp   = (unsigned*)d_out;

    // counts+tail := 0 ; mm := 0xFFFFFFFF (both accumulate via atomicMin)
    hipMemsetAsync(counts, 0, ((size_t)NBINS + 1) * 4, stream);
    hipMemsetAsync(mm, 0xFF, 8, stream);
    hipMemsetAsync(d_out, 0, (size_t)out_size * sizeof(float), stream);

    size_t need = ((size_t)NBINS + 4 + 2 * (size_t)ntot) * 4;
    if (ws_size < need) {
        hipLaunchKernelGGL(k_minmax, dim3(512), dim3(256), 0, stream,
                           pts, npts3, mm);
        hipLaunchKernelGGL(scatter_kernel, dim3((ntot + 3) / 4), dim3(256), 0,
                           stream, pts, feat, mm, outp, ntot, N);
        return;
    }

    int dev = 0, coop = 0;
    (void)hipGetDevice(&dev);
    (void)hipDeviceGetAttribute(&coop, hipDeviceAttributeCooperativeLaunch, dev);

    if (coop) {
        void* args[] = {(void*)&pts, (void*)&feat, (void*)&ws, (void*)&outp,
                        (void*)&ntot, (void*)&npts3, (void*)&N};
        hipLaunchCooperativeKernel((void*)fused_kernel, dim3(BLOCKS), dim3(TPB),
                                   args, 0, stream);
    } else {
        hipLaunchKernelGGL(k_minmax, dim3(BLOCKS), dim3(TPB), 0, stream,
                           pts, npts3, mm);
        hipLaunchKernelGGL(k_bincount, dim3(BLOCKS), dim3(TPB), 0, stream,
                           pts, mm, counts, ntot, N);
        hipLaunchKernelGGL(k_offsets, dim3(BLOCKS), dim3(TPB), 0, stream,
                           counts, tail);
        hipLaunchKernelGGL(k_build, dim3(BLOCKS), dim3(TPB), 0, stream,
                           pts, mm, counts, ord2, ntot, N);
        hipLaunchKernelGGL(k_gather, dim3(BLOCKS), dim3(TPB), 0, stream,
                           feat, ord2, ntot, outp);
    }
}

// Round 6
// 665.361 us; speedup vs baseline: 1.1253x; 1.1253x over previous
//
#include <hip/hip_runtime.h>

#define SPATIAL 32768   // 32^3
#define FDIM    64
#define TPB     256
#define MAXBLK  2048

// ws word layout:
//   [0]                  ctr   (grid-barrier counter; host memsets 4 B to 0)
//   [1]                  tail
//   [2..3]               norm  (pmin, pmax floats; used by split/tiny paths)
//   [4, 4+2*MAXBLK)      partials (float2 per block)
//   [4+2*MAXBLK, +nbins) counts -> offsets -> cursor (in place)
//   then                 ord2: uint2 (point, bin), bin-grouped, 8B aligned

// ---------------- custom grid barrier (cooperative path) ----------------
// syncthreads drains every wave's stores to L2 (compiler emits vmcnt(0) before
// s_barrier). Thread 0: RELEASE atomicAdd (one L2 writeback), RELAXED polling
// (no per-poll invalidate -- the suspected cg::grid.sync pathology), one
// ACQUIRE load (single buffer_inv) on exit.
__device__ __forceinline__ void gbar(unsigned* ctr, unsigned target) {
    __syncthreads();
    if (threadIdx.x == 0) {
        __hip_atomic_fetch_add(ctr, 1u, __ATOMIC_RELEASE,
                               __HIP_MEMORY_SCOPE_AGENT);
        while (__hip_atomic_load(ctr, __ATOMIC_RELAXED,
                                 __HIP_MEMORY_SCOPE_AGENT) < target)
            __builtin_amdgcn_s_sleep(8);
        (void)__hip_atomic_load(ctr, __ATOMIC_ACQUIRE,
                                __HIP_MEMORY_SCOPE_AGENT);
    }
    __syncthreads();
}

// ---------------- helpers ----------------
__device__ __forceinline__ unsigned compute_bin(const float* __restrict__ pts,
                                                int p, int N,
                                                float pmin, float denom) {
    float x = pts[p * 3 + 0];
    float y = pts[p * 3 + 1];
    float z = pts[p * 3 + 2];
    // exact op order of reference: normed = (v-pmin)/denom; floor(normed*32)
    int vx = (int)floorf(((x - pmin) / denom) * 32.0f);
    int vy = (int)floorf(((y - pmin) / denom) * 32.0f);
    int vz = (int)floorf(((z - pmin) / denom) * 32.0f);
    vx = min(max(vx, 0), 31);
    vy = min(max(vy, 0), 31);
    vz = min(max(vz, 0), 31);
    int b = p / N;
    return (unsigned)b * SPATIAL + (unsigned)(vx * 1024 + vy * 32 + vz);
}

__device__ __forceinline__ float2 block_minmax(float lmin, float lmax) {
#pragma unroll
    for (int d = 1; d < 64; d <<= 1) {
        lmin = fminf(lmin, __shfl_xor(lmin, d, 64));
        lmax = fmaxf(lmax, __shfl_xor(lmax, d, 64));
    }
    __shared__ float smn[TPB / 64], smx[TPB / 64];
    int wid = threadIdx.x >> 6;
    if ((threadIdx.x & 63) == 0) { smn[wid] = lmin; smx[wid] = lmax; }
    __syncthreads();
    float2 r;
    r.x = fminf(fminf(smn[0], smn[1]), fminf(smn[2], smn[3]));
    r.y = fmaxf(fmaxf(smx[0], smx[1]), fmaxf(smx[2], smx[3]));
    __syncthreads();
    return r;
}

// ---------------- phases ----------------
__device__ void ph_zero_minmax(const float* __restrict__ pts, int npts3,
                               float* __restrict__ out, int nout,
                               unsigned* __restrict__ counts, int nbins,
                               unsigned* __restrict__ tail,
                               float2* __restrict__ partials,
                               int tid, int nth) {
    float4 z = make_float4(0.f, 0.f, 0.f, 0.f);
    float4* o4 = (float4*)out;
    int nout4 = nout >> 2;
    for (int i = tid; i < nout4; i += nth) o4[i] = z;
    for (int i = tid; i < nbins; i += nth) counts[i] = 0u;
    if (tid == 0) *tail = 0u;

    float lmin = INFINITY, lmax = -INFINITY;
    const float4* p4 = (const float4*)pts;
    int n4 = npts3 >> 2;
    for (int i = tid; i < n4; i += nth) {
        float4 v = p4[i];
        lmin = fminf(fminf(lmin, v.x), fminf(v.y, v.z)); lmin = fminf(lmin, v.w);
        lmax = fmaxf(fmaxf(lmax, v.x), fmaxf(v.y, v.z)); lmax = fmaxf(lmax, v.w);
    }
    for (int i = (n4 << 2) + tid; i < npts3; i += nth) {
        float v = pts[i];
        lmin = fminf(lmin, v); lmax = fmaxf(lmax, v);
    }
    float2 bm = block_minmax(lmin, lmax);
    if (threadIdx.x == 0) partials[blockIdx.x] = bm;
}

// every block reduces the same partials in the same order -> bit-identical
__device__ float2 reduce_partials(const float2* __restrict__ partials,
                                  int nblk) {
    float lmin = INFINITY, lmax = -INFINITY;
    for (int i = threadIdx.x; i < nblk; i += TPB) {
        float2 v = partials[i];
        lmin = fminf(lmin, v.x);
        lmax = fmaxf(lmax, v.y);
    }
    return block_minmax(lmin, lmax);
}

__device__ void ph_bincount(const float* __restrict__ pts, int ntot, int N,
                            float pmin, float denom,
                            unsigned* __restrict__ counts, int tid, int nth) {
    for (int p = tid; p < ntot; p += nth)
        atomicAdd(&counts[compute_bin(pts, p, N, pmin, denom)], 1u);
}

__device__ void ph_offsets(unsigned* __restrict__ counts, int nbins,
                           unsigned* __restrict__ tail, int tid, int nth) {
    int lane = threadIdx.x & 63;
    for (int i = tid; i < nbins; i += nth) {   // nbins, nth multiples of 64
        unsigned cnt = counts[i];
        unsigned cs = cnt;
#pragma unroll
        for (int d = 1; d < 64; d <<= 1) {
            unsigned v = __shfl_up(cs, (unsigned)d, 64);
            if (lane >= d) cs += v;
        }
        unsigned ctot = __shfl(cs, 63, 64);
        unsigned base = 0;
        if (lane == 63 && ctot) base = atomicAdd(tail, ctot);
        base = __shfl(base, 63, 64);
        if (cnt) counts[i] = base + cs - cnt;   // exclusive offset
    }
}

__device__ void ph_build(const float* __restrict__ pts, int ntot, int N,
                         float pmin, float denom,
                         unsigned* __restrict__ cursor,
                         uint2* __restrict__ ord2, int tid, int nth) {
    for (int p = tid; p < ntot; p += nth) {
        unsigned bin = compute_bin(pts, p, N, pmin, denom);
        unsigned pos = atomicAdd(&cursor[bin], 1u);
        ord2[pos] = make_uint2((unsigned)p, bin);
    }
}

// chunk-balanced gather: wave takes 64-slot chunks of bin-grouped (point,bin);
// runs of equal bin fold in-register, flush = one wave-wide atomicMax.
__device__ void ph_gather(const float* __restrict__ feat,
                          const uint2* __restrict__ ord2, int ntot,
                          unsigned* __restrict__ out, int tid, int nth) {
    int lane = threadIdx.x & 63;
    unsigned wave = (unsigned)tid >> 6;
    unsigned nwaves = (unsigned)nth >> 6;
    unsigned nchunks = ((unsigned)ntot + 63u) >> 6;

    for (unsigned c = wave; c < nchunks; c += nwaves) {
        unsigned base = c << 6;
        unsigned nb = min(64u, (unsigned)ntot - base);
        uint2 e = (lane < (int)nb) ? ord2[base + lane]
                                   : make_uint2(0u, 0xFFFFFFFFu);
        unsigned pv = e.x;
        unsigned bv = e.y;

        float m = 0.0f;   // zero-init grid == implicit max with 0
        for (unsigned j0 = 0; j0 < nb; j0 += 16) {
            unsigned kn = min(16u, nb - j0);
            float f[16];
#pragma unroll
            for (unsigned k = 0; k < 16; ++k) {
                if (k < kn) {
                    unsigned p = __shfl(pv, (int)(j0 + k), 64);
                    f[k] = feat[(size_t)p * FDIM + lane];
                }
            }
#pragma unroll
            for (unsigned k = 0; k < 16; ++k) {
                if (k < kn) {
                    unsigned idx = j0 + k;
                    unsigned b  = __shfl(bv, (int)idx, 64);
                    unsigned bn = (idx + 1 < nb)
                                      ? __shfl(bv, (int)(idx + 1), 64)
                                      : 0xFFFFFFFFu;
                    m = fmaxf(m, f[k]);
                    if (b != bn) {   // wave-uniform
                        if (m > 0.0f)
                            atomicMax(&out[(size_t)b * FDIM + lane],
                                      __float_as_uint(m));
                        m = 0.0f;
                    }
                }
            }
        }
    }
}

// ---------------- fused cooperative kernel ----------------
__global__ void __launch_bounds__(TPB, 8)
fused_kernel(const float* __restrict__ pts, const float* __restrict__ feat,
             unsigned* __restrict__ ws, float* __restrict__ out,
             int ntot, int npts3, int N, int nbins, int nout, unsigned nblk) {
    unsigned* ctr  = ws;
    unsigned* tail = ws + 1;
    float2* partials = (float2*)(ws + 4);
    unsigned* counts = ws + 4 + 2 * MAXBLK;
    uint2* ord2 = (uint2*)(counts + nbins);

    int tid = blockIdx.x * TPB + threadIdx.x;
    int nth = (int)nblk * TPB;

    ph_zero_minmax(pts, npts3, out, nout, counts, nbins, tail, partials,
                   tid, nth);
    gbar(ctr, 1u * nblk);
    float2 mm = reduce_partials(partials, (int)nblk);
    float pmin = mm.x;
    float denom = mm.y - mm.x + 1e-6f;
    ph_bincount(pts, ntot, N, pmin, denom, counts, tid, nth);
    gbar(ctr, 2u * nblk);
    ph_offsets(counts, nbins, tail, tid, nth);
    gbar(ctr, 3u * nblk);
    ph_build(pts, ntot, N, pmin, denom, counts, ord2, tid, nth);
    gbar(ctr, 4u * nblk);
    ph_gather(feat, ord2, ntot, (unsigned*)out, tid, nth);
}

// ---------------- split-dispatch fallback ----------------
__global__ void k0_zero_minmax(const float* pts, int npts3, float* out,
                               int nout, unsigned* counts, int nbins,
                               unsigned* tail, float2* partials) {
    ph_zero_minmax(pts, npts3, out, nout, counts, nbins, tail, partials,
                   blockIdx.x * TPB + threadIdx.x, gridDim.x * TPB);
}
__global__ void k1_bincount(const float* pts, int ntot, int N,
                            const float2* partials, int nblk0,
                            unsigned* counts, float* norm) {
    float2 mm = reduce_partials(partials, nblk0);
    if (blockIdx.x == 0 && threadIdx.x == 0) {
        norm[0] = mm.x; norm[1] = mm.y;
    }
    ph_bincount(pts, ntot, N, mm.x, mm.y - mm.x + 1e-6f, counts,
                blockIdx.x * TPB + threadIdx.x, gridDim.x * TPB);
}
__global__ void k2_offsets(unsigned* counts, int nbins, unsigned* tail) {
    ph_offsets(counts, nbins, tail, blockIdx.x * TPB + threadIdx.x,
               gridDim.x * TPB);
}
__global__ void k3_build(const float* pts, int ntot, int N, const float* norm,
                         unsigned* cursor, uint2* ord2) {
    float pmin = norm[0];
    float denom = norm[1] - pmin + 1e-6f;
    ph_build(pts, ntot, N, pmin, denom, cursor, ord2,
             blockIdx.x * TPB + threadIdx.x, gridDim.x * TPB);
}
__global__ void k4_gather(const float* feat, const uint2* ord2, int ntot,
                          unsigned* out) {
    ph_gather(feat, ord2, ntot, out, blockIdx.x * TPB + threadIdx.x,
              gridDim.x * TPB);
}
// tiny-ws last resort: direct atomic scatter
__global__ void k_scatter(const float* pts, const float* feat,
                          const float* norm, unsigned* out, int ntot, int N) {
    int lane = threadIdx.x & 63;
    int p = blockIdx.x * 4 + (threadIdx.x >> 6);
    if (p >= ntot) return;
    float pmin = norm[0];
    float denom = norm[1] - pmin + 1e-6f;
    unsigned bin = compute_bin(pts, p, N, pmin, denom);
    float f = feat[(size_t)p * FDIM + lane];
    if (f > 0.0f)
        atomicMax(&out[(size_t)bin * FDIM + lane], __float_as_uint(f));
}

extern "C" void kernel_launch(void* const* d_in, const int* in_sizes, int n_in,
                              void* d_out, int out_size, void* d_ws, size_t ws_size,
                              hipStream_t stream) {
    const float* pts = (const float*)d_in[0];
    const float* feat = (const float*)d_in[1];

    int npts3 = in_sizes[0];            // B*N*3
    int ntot = npts3 / 3;               // B*N
    int B = out_size / (SPATIAL * FDIM);
    int N = ntot / B;
    int nbins = B * SPATIAL;
    int nout = out_size;

    unsigned* ws = (unsigned*)d_ws;
    unsigned* ctr  = ws;
    unsigned* tail = ws + 1;
    float* norm = (float*)(ws + 2);
    float2* partials = (float2*)(ws + 4);
    unsigned* counts = ws + 4 + 2 * MAXBLK;
    uint2* ord2 = (uint2*)(counts + nbins);
    float* outp = (float*)d_out;
    unsigned* outu = (unsigned*)d_out;

    size_t need = ((size_t)4 + 2 * MAXBLK + (size_t)nbins) * 4
                + (size_t)ntot * 8;

    if (ws_size < need) {
        // tiny path: zero+minmax, reduce->norm, atomic scatter
        hipLaunchKernelGGL(k0_zero_minmax, dim3(512), dim3(TPB), 0, stream,
                           pts, npts3, outp, nout, ws + 4, 0, tail, partials);
        hipLaunchKernelGGL(k1_bincount, dim3(1), dim3(TPB), 0, stream,
                           pts, 0, N, partials, 512, ws + 4, norm);
        hipLaunchKernelGGL(k_scatter, dim3((ntot + 3) / 4), dim3(TPB), 0,
                           stream, pts, feat, norm, outu, ntot, N);
        return;
    }

    int dev = 0, coop = 0, cus = 0, occ = 0;
    (void)hipGetDevice(&dev);
    (void)hipDeviceGetAttribute(&coop, hipDeviceAttributeCooperativeLaunch, dev);
    (void)hipDeviceGetAttribute(&cus, hipDeviceAttributeMultiprocessorCount, dev);
    (void)hipOccupancyMaxActiveBlocksPerMultiprocessor(&occ, (const void*)fused_kernel,
                                                       TPB, 0);
    long nblk_l = (long)occ * (long)cus;
    int nblk = (nblk_l > MAXBLK) ? MAXBLK : (int)nblk_l;

    bool launched = false;
    if (coop && nblk >= 256) {
        unsigned nblku = (unsigned)nblk;
        hipMemsetAsync(ctr, 0, 4, stream);
        void* args[] = {(void*)&pts, (void*)&feat, (void*)&ws, (void*)&outp,
                        (void*)&ntot, (void*)&npts3, (void*)&N, (void*)&nbins,
                        (void*)&nout, (void*)&nblku};
        hipError_t err = hipLaunchCooperativeKernel((void*)fused_kernel,
                                                    dim3(nblk), dim3(TPB),
                                                    args, 0, stream);
        launched = (err == hipSuccess);
    }
    if (!launched) {
        const int NB = 1024;
        hipLaunchKernelGGL(k0_zero_minmax, dim3(NB), dim3(TPB), 0, stream,
                           pts, npts3, outp, nout, counts, nbins, tail,
                           partials);
        hipLaunchKernelGGL(k1_bincount, dim3(NB), dim3(TPB), 0, stream,
                           pts, ntot, N, partials, NB, counts, norm);
        hipLaunchKernelGGL(k2_offsets, dim3(NB), dim3(TPB), 0, stream,
                           counts, nbins, tail);
        hipLaunchKernelGGL(k3_build, dim3(NB), dim3(TPB), 0, stream,
                           pts, ntot, N, norm, counts, ord2);
        hipLaunchKernelGGL(k4_gather, dim3(NB), dim3(TPB), 0, stream,
                           feat, ord2, ntot, outu);
    }
}